// Round 15
// baseline (256.326 us; speedup 1.0000x reference)
//
#include <hip/hip_runtime.h>
#include <math.h>

#define B_ 4
#define N_ 256
#define D_ 128
#define H_ 256
#define K_ 8
#define NJP 64    // j per phase (4 phases)

typedef short v8s __attribute__((ext_vector_type(8)));    // 8 bf16 = 4 VGPRs
typedef float v16f __attribute__((ext_vector_type(16)));  // 32x32 MFMA acc

// hi = top-16-bit truncation (x - hi is EXACT); lo = RNE bf16 of remainder.
__device__ inline void split_bf16(float x, unsigned short& hi, unsigned short& lo) {
  unsigned u = __float_as_uint(x);
  unsigned uh = u & 0xFFFF0000u;
  hi = (unsigned short)(uh >> 16);
  float r = x - __uint_as_float(uh);
  unsigned ur = __float_as_uint(r);
  ur += 0x7FFFu + ((ur >> 16) & 1u);
  lo = (unsigned short)(ur >> 16);
}

// ---------------------------------------------------------------------------
// prep_all v15: ONE launch, and the Ag/Aa part is n-TILED (16 rows per
// block) so each W element is read once per 16 n instead of once per n:
// W traffic 268 MB -> 17 MB (R14's prep was W-read-bound, ~26us).
//  blocks 0..63   : Ag/Aa tiled (b = blk>>4, ntile = blk&15)
//  blocks 64..191 : W -> MFMA-B fragment order [ks(16)][tile(8)][lane][8]
//  blocks 192..223: sj half of A -> MFMA-A fragment order
// ---------------------------------------------------------------------------
__global__ __launch_bounds__(256) void prep_all(
    const float* __restrict__ s,
    const float* __restrict__ Wg1, const float* __restrict__ bg1,
    const float* __restrict__ Wa1, const float* __restrict__ ba1,
    float* __restrict__ Ag, float* __restrict__ Aa,
    unsigned short* __restrict__ Wghi, unsigned short* __restrict__ Wglo,
    unsigned short* __restrict__ Wahi,
    unsigned short* __restrict__ Sfh, unsigned short* __restrict__ Sfl) {
  __shared__ float sh2[16 * D_];   // 8 KB
  const int blk = blockIdx.x;
  const int t = threadIdx.x;
  if (blk < 64) {
    const int b = blk >> 4, nt = blk & 15, h = t;
#pragma unroll
    for (int u = 0; u < 8; u++)
      sh2[u * 256 + t] = s[(b * N_ + nt * 16) * D_ + u * 256 + t];
    __syncthreads();
    float ag[16], aa[16];
#pragma unroll
    for (int n = 0; n < 16; n++) { ag[n] = bg1[h]; aa[n] = ba1[h]; }
#pragma unroll 4
    for (int d = 0; d < D_; d++) {
      const float wg = Wg1[d * H_ + h];
      const float wa = Wa1[d * H_ + h];
#pragma unroll
      for (int n = 0; n < 16; n++) {
        const float sv = sh2[n * D_ + d];
        ag[n] = fmaf(sv, wg, ag[n]);
        aa[n] = fmaf(sv, wa, aa[n]);
      }
    }
#pragma unroll
    for (int n = 0; n < 16; n++) {
      Ag[(b * N_ + nt * 16 + n) * H_ + h] = ag[n];
      Aa[(b * N_ + nt * 16 + n) * H_ + h] = aa[n];
    }
  } else if (blk < 192) {
    const int id = blk - 64;            // 0..127
    if (t < 64) {
      const int ks = id >> 3, tile = id & 7, lane = t;
      const int h = tile * 32 + (lane & 31);
      const int kbase = ks * 16 + (lane >> 5) * 8;
      const int idx0 = (id * 64 + lane) * 8;
#pragma unroll
      for (int e = 0; e < 8; e++) {
        const int k = kbase + e;
        const int f = (k < D_) ? (2 * D_ + k) : k;
        unsigned short x, y;
        split_bf16(Wg1[f * H_ + h], x, y);
        Wghi[idx0 + e] = x;
        Wglo[idx0 + e] = y;
        unsigned short xa, ya;
        split_bf16(Wa1[f * H_ + h], xa, ya);
        Wahi[idx0 + e] = xa;
      }
    }
  } else {
    const int id = blk - 192;           // 0..31
    const int b = id >> 3, jt = id & 7;
    const int lane = t & 63, k0 = t >> 6;
    const int j = jt * 32 + (lane & 31);
#pragma unroll
    for (int ksl = k0; ksl < 8; ksl += 4) {
      const int d = ksl * 16 + (lane >> 5) * 8;
      const float* sp = s + (b * N_ + j) * D_ + d;
      const float4 f0 = *(const float4*)(sp);
      const float4 f1 = *(const float4*)(sp + 4);
      v8s vh, vl;
      unsigned short x, y;
      split_bf16(f0.x, x, y); vh[0] = (short)x; vl[0] = (short)y;
      split_bf16(f0.y, x, y); vh[1] = (short)x; vl[1] = (short)y;
      split_bf16(f0.z, x, y); vh[2] = (short)x; vl[2] = (short)y;
      split_bf16(f0.w, x, y); vh[3] = (short)x; vl[3] = (short)y;
      split_bf16(f1.x, x, y); vh[4] = (short)x; vl[4] = (short)y;
      split_bf16(f1.y, x, y); vh[5] = (short)x; vl[5] = (short)y;
      split_bf16(f1.z, x, y); vh[6] = (short)x; vl[6] = (short)y;
      split_bf16(f1.w, x, y); vh[7] = (short)x; vl[7] = (short)y;
      const int dst = (((b * 8 + jt) * 8 + ksl) * 64 + lane) * 8;
      *(v8s*)(Sfh + dst) = vh;
      *(v8s*)(Sfl + dst) = vl;
    }
  }
}

__device__ inline void arg_better(float v2, int i2, float& v, int& idx) {
  if (v2 > v || (v2 == v && i2 < idx)) { v = v2; idx = i2; }
}

// LDS A-tile (P part, k<128) fragment-order index: jl (0..63), k (0..127)
__device__ inline int a_idx(int jl, int k) {
  return (((jl >> 5) * 8 + (k >> 4)) * 64 + ((k >> 3) & 1) * 32 + (jl & 31)) * 8
         + (k & 7);
}
#define ALO 8192   // shorts offset of lo half

// ---------------------------------------------------------------------------
// score_kernel v14 (unchanged — best known: 185us, absmax 0.0078):
// single i per block, gate+att merged into one k-loop; each A-fragment read
// feeds 16 MFMAs (12 gate split-3 + 4 att hi-only). acc = 128 AGPR.
// ---------------------------------------------------------------------------
__global__ __launch_bounds__(256, 2) void score_kernel(
    const float* __restrict__ s,
    const float* __restrict__ Ag, const float* __restrict__ Aa,
    const unsigned short* __restrict__ Sfh, const unsigned short* __restrict__ Sfl,
    const unsigned short* __restrict__ Wghi, const unsigned short* __restrict__ Wglo,
    const unsigned short* __restrict__ Wahi,
    const float* __restrict__ Wg2, const float* __restrict__ bg2p,
    const float* __restrict__ Wa2, const float* __restrict__ ba2p,
    float* __restrict__ out) {
  const int b = blockIdx.x >> 8;
  const int i = blockIdx.x & 255;
  const int t = threadIdx.x;
  const int wv = t >> 6, lane = t & 63;
  const int m32 = lane & 31, half32 = lane >> 5;

  __shared__ __align__(16) unsigned short a_all[2 * ALO + 64]; // P hi|lo 32KB
  __shared__ float si_sh[D_];
  __shared__ float sc_part[8 * NJP];   // [0..3]=gate per wave, [4..7]=att
  __shared__ float scg_sh[N_];
  __shared__ float attl_sh[N_];
  __shared__ float red_v[4];
  __shared__ int red_i[4];
  __shared__ int sel_list[K_];

  if (t < D_) si_sh[t] = s[(b * N_ + i) * D_ + t];

  float agv[2], w2g[2], aav[2], w2a[2];
#pragma unroll
  for (int ht = 0; ht < 2; ht++) {
    const int hg = wv * 64 + ht * 32 + m32;
    agv[ht] = Ag[(b * N_ + i) * H_ + hg];
    w2g[ht] = Wg2[hg];
    aav[ht] = Aa[(b * N_ + i) * H_ + hg];
    w2a[ht] = Wa2[hg];
  }

  const int boff = ((2 * wv) * 64 + lane) * 8;   // tile pair base; +512 = tile1

#define MF(A_, B_v, C_) C_ = __builtin_amdgcn_mfma_f32_32x32x16_bf16(A_, B_v, C_, 0, 0, 0)

#pragma unroll 1
  for (int ph = 0; ph < 4; ph++) {
    __syncthreads();
    // ---- stage P tile (frag order, k<128 only) ----
    {
      const int jl = t >> 2, kq = t & 3;
      const int jg = b * N_ + ph * NJP + jl;
      const float* srow = s + jg * D_ + kq * 32;
      const float* sic = si_sh + kq * 32;
#pragma unroll
      for (int u = 0; u < 4; u++) {   // 8 k per u
        const float4 sv0 = *(const float4*)(srow + u * 8);
        const float4 sv1 = *(const float4*)(srow + u * 8 + 4);
        v8s vh, vl;
        unsigned short x, y;
        split_bf16(sic[u * 8 + 0] * sv0.x, x, y); vh[0] = (short)x; vl[0] = (short)y;
        split_bf16(sic[u * 8 + 1] * sv0.y, x, y); vh[1] = (short)x; vl[1] = (short)y;
        split_bf16(sic[u * 8 + 2] * sv0.z, x, y); vh[2] = (short)x; vl[2] = (short)y;
        split_bf16(sic[u * 8 + 3] * sv0.w, x, y); vh[3] = (short)x; vl[3] = (short)y;
        split_bf16(sic[u * 8 + 4] * sv1.x, x, y); vh[4] = (short)x; vl[4] = (short)y;
        split_bf16(sic[u * 8 + 5] * sv1.y, x, y); vh[5] = (short)x; vl[5] = (short)y;
        split_bf16(sic[u * 8 + 6] * sv1.z, x, y); vh[6] = (short)x; vl[6] = (short)y;
        split_bf16(sic[u * 8 + 7] * sv1.w, x, y); vh[7] = (short)x; vl[7] = (short)y;
        const int idx = a_idx(jl, kq * 32 + u * 8);
        *(v8s*)(a_all + idx) = vh;
        *(v8s*)(a_all + ALO + idx) = vl;
      }
    }
    __syncthreads();

    const unsigned short* sf_base_h = Sfh + ((b * 8 + ph * 2) * 8) * 512 + lane * 8;
    const unsigned short* sf_base_l = Sfl + ((b * 8 + ph * 2) * 8) * 512 + lane * 8;

    // ========== merged k-loop: gate (split-3) + att (hi) together ==========
    v16f g00, g01, g10, g11, a00, a01, a10, a11;   // [jt][ht] — 128 AGPR
    g00 = g01 = g10 = g11 = (v16f)(0.f);
    a00 = a01 = a10 = a11 = (v16f)(0.f);

    {
      const unsigned short* pgh = Wghi + boff;
      const unsigned short* pgl = Wglo + boff;
      const unsigned short* pah = Wahi + boff;
      v8s bh[2][2], bl[2][2], ba[2][2];
      bh[0][0] = *(const v8s*)pgh;  bh[0][1] = *(const v8s*)(pgh + 512);
      bl[0][0] = *(const v8s*)pgl;  bl[0][1] = *(const v8s*)(pgl + 512);
      ba[0][0] = *(const v8s*)pah;  ba[0][1] = *(const v8s*)(pah + 512);
      pgh += 4096;  pgl += 4096;  pah += 4096;

      const unsigned short* ahp = a_all + lane * 8;
      // ---- loop1: ks 0..7, A from LDS (P part) ----
#pragma unroll 2
      for (int ks = 0; ks < 8; ks++) {
        const int cur = ks & 1, nxt = cur ^ 1;
        bh[nxt][0] = *(const v8s*)pgh;  bh[nxt][1] = *(const v8s*)(pgh + 512);
        bl[nxt][0] = *(const v8s*)pgl;  bl[nxt][1] = *(const v8s*)(pgl + 512);
        ba[nxt][0] = *(const v8s*)pah;  ba[nxt][1] = *(const v8s*)(pah + 512);
        pgh += 4096;  pgl += 4096;  pah += 4096;
        v8s ah0 = *(const v8s*)(ahp);
        v8s ah1 = *(const v8s*)(ahp + 4096);
        v8s al0 = *(const v8s*)(ahp + ALO);
        v8s al1 = *(const v8s*)(ahp + ALO + 4096);
        ahp += 512;
        MF(ah0, bh[cur][0], g00); MF(ah0, bh[cur][1], g01);
        MF(ah0, ba[cur][0], a00); MF(ah0, ba[cur][1], a01);
        MF(ah0, bl[cur][0], g00); MF(ah0, bl[cur][1], g01);
        MF(al0, bh[cur][0], g00); MF(al0, bh[cur][1], g01);
        MF(ah1, bh[cur][0], g10); MF(ah1, bh[cur][1], g11);
        MF(ah1, ba[cur][0], a10); MF(ah1, ba[cur][1], a11);
        MF(ah1, bl[cur][0], g10); MF(ah1, bl[cur][1], g11);
        MF(al1, bh[cur][0], g10); MF(al1, bh[cur][1], g11);
      }
      // ---- loop2: ks 8..15, A from global sj frag streams ----
      const unsigned short* sfh = sf_base_h;
      const unsigned short* sfl = sf_base_l;
#pragma unroll 2
      for (int ks = 8; ks < 16; ks++) {
        const int cur = ks & 1, nxt = cur ^ 1;
        bh[nxt][0] = *(const v8s*)pgh;  bh[nxt][1] = *(const v8s*)(pgh + 512);
        bl[nxt][0] = *(const v8s*)pgl;  bl[nxt][1] = *(const v8s*)(pgl + 512);
        ba[nxt][0] = *(const v8s*)pah;  ba[nxt][1] = *(const v8s*)(pah + 512);
        pgh += 4096;  pgl += 4096;  pah += 4096;   // last iter reads pad
        v8s ah0 = *(const v8s*)(sfh);
        v8s ah1 = *(const v8s*)(sfh + 4096);
        v8s al0 = *(const v8s*)(sfl);
        v8s al1 = *(const v8s*)(sfl + 4096);
        sfh += 512;  sfl += 512;
        MF(ah0, bh[cur][0], g00); MF(ah0, bh[cur][1], g01);
        MF(ah0, ba[cur][0], a00); MF(ah0, ba[cur][1], a01);
        MF(ah0, bl[cur][0], g00); MF(ah0, bl[cur][1], g01);
        MF(al0, bh[cur][0], g00); MF(al0, bh[cur][1], g01);
        MF(ah1, bh[cur][0], g10); MF(ah1, bh[cur][1], g11);
        MF(ah1, ba[cur][0], a10); MF(ah1, ba[cur][1], a11);
        MF(ah1, bl[cur][0], g10); MF(ah1, bl[cur][1], g11);
        MF(al1, bh[cur][0], g10); MF(al1, bh[cur][1], g11);
      }
    }

    // ---- merged epilogue: relu + W2 dot, 16-lane butterfly, both nets ----
    {
      float sg[32];
#pragma unroll
      for (int m = 0; m < 32; m++) sg[m] = 0.f;
#pragma unroll
      for (int r = 0; r < 16; r++) {
        sg[r]      = fmaf(fmaxf(g00[r] + agv[0], 0.f), w2g[0], sg[r]);
        sg[r]      = fmaf(fmaxf(g01[r] + agv[1], 0.f), w2g[1], sg[r]);
        sg[16 + r] = fmaf(fmaxf(g10[r] + agv[0], 0.f), w2g[0], sg[16 + r]);
        sg[16 + r] = fmaf(fmaxf(g11[r] + agv[1], 0.f), w2g[1], sg[16 + r]);
      }
#pragma unroll
      for (int m = 0; m < 32; m++) {
        float v = sg[m];
#pragma unroll
        for (int off = 1; off <= 16; off <<= 1) v += __shfl_xor(v, off, 64);
        sg[m] = v;
      }
      if (m32 == 0) {
#pragma unroll
        for (int jt = 0; jt < 2; jt++)
#pragma unroll
          for (int r = 0; r < 16; r++) {
            const int jl = jt * 32 + (r & 3) + 8 * (r >> 2) + 4 * half32;
            sc_part[wv * NJP + jl] = sg[jt * 16 + r];
          }
      }
      float sa[32];
#pragma unroll
      for (int m = 0; m < 32; m++) sa[m] = 0.f;
#pragma unroll
      for (int r = 0; r < 16; r++) {
        sa[r]      = fmaf(fmaxf(a00[r] + aav[0], 0.f), w2a[0], sa[r]);
        sa[r]      = fmaf(fmaxf(a01[r] + aav[1], 0.f), w2a[1], sa[r]);
        sa[16 + r] = fmaf(fmaxf(a10[r] + aav[0], 0.f), w2a[0], sa[16 + r]);
        sa[16 + r] = fmaf(fmaxf(a11[r] + aav[1], 0.f), w2a[1], sa[16 + r]);
      }
#pragma unroll
      for (int m = 0; m < 32; m++) {
        float v = sa[m];
#pragma unroll
        for (int off = 1; off <= 16; off <<= 1) v += __shfl_xor(v, off, 64);
        sa[m] = v;
      }
      if (m32 == 0) {
#pragma unroll
        for (int jt = 0; jt < 2; jt++)
#pragma unroll
          for (int r = 0; r < 16; r++) {
            const int jl = jt * 32 + (r & 3) + 8 * (r >> 2) + 4 * half32;
            sc_part[4 * NJP + wv * NJP + jl] = sa[jt * 16 + r];
          }
      }
    }
    __syncthreads();
    if (t < NJP) {
      scg_sh[ph * NJP + t] = sc_part[t] + sc_part[NJP + t] + sc_part[2 * NJP + t]
                           + sc_part[3 * NJP + t] + bg2p[0];
      attl_sh[ph * NJP + t] = sc_part[4 * NJP + t] + sc_part[5 * NJP + t]
                            + sc_part[6 * NJP + t] + sc_part[7 * NJP + t] + ba2p[0];
    }
  }
  __syncthreads();

  // ---- top-8 over j: value desc, index asc ----
  for (int k = 0; k < K_; k++) {
    float v = scg_sh[t];
    int idx = t;
#pragma unroll
    for (int off = 32; off > 0; off >>= 1) {
      const float vo = __shfl_down(v, off, 64);
      const int io = __shfl_down(idx, off, 64);
      arg_better(vo, io, v, idx);
    }
    if ((t & 63) == 0) { red_v[t >> 6] = v; red_i[t >> 6] = idx; }
    __syncthreads();
    if (t == 0) {
      float bv = red_v[0];
      int bi = red_i[0];
      for (int w = 1; w < 4; w++) arg_better(red_v[w], red_i[w], bv, bi);
      sel_list[k] = bi;
      scg_sh[bi] = -INFINITY;
    }
    __syncthreads();
  }

  bool selj = false;
#pragma unroll
  for (int k = 0; k < K_; k++) selj = selj || (sel_list[k] == t);

  if (t == 0) {
    float m = -INFINITY;
    for (int k = 0; k < K_; k++) m = fmaxf(m, attl_sh[sel_list[k]]);
    float ssum = 0.f;
    for (int k = 0; k < K_; k++) ssum += expf(attl_sh[sel_list[k]] - m);
    red_v[0] = m;
    red_v[1] = ssum;
  }
  __syncthreads();
  const float att = selj ? expf(attl_sh[t] - red_v[0]) / red_v[1] : 0.f;

  float* __restrict__ ctx_out = out;
  float* __restrict__ gate_out = out + B_ * N_ * D_;
  float* __restrict__ att_out = out + B_ * N_ * D_ + B_ * N_ * N_;

  const int row = (b * N_ + i) * N_;
  gate_out[row + t] = selj ? 1.f : 0.f;
  att_out[row + t] = att;

  __syncthreads();
  attl_sh[t] = att;
  __syncthreads();

  if (t < D_) {
    float acc2 = 0.f;
#pragma unroll
    for (int k = 0; k < K_; k++) {
      const int jj = sel_list[k];
      acc2 = fmaf(attl_sh[jj], s[(b * N_ + jj) * D_ + t], acc2);
    }
    ctx_out[(b * N_ + i) * D_ + t] = acc2;
  }
#undef MF
}

extern "C" void kernel_launch(void* const* d_in, const int* in_sizes, int n_in,
                              void* d_out, int out_size, void* d_ws, size_t ws_size,
                              hipStream_t stream) {
  const float* s   = (const float*)d_in[0];
  const float* Wg1 = (const float*)d_in[1];
  const float* bg1 = (const float*)d_in[2];
  const float* Wg2 = (const float*)d_in[3];
  const float* bg2 = (const float*)d_in[4];
  const float* Wa1 = (const float*)d_in[5];
  const float* ba1 = (const float*)d_in[6];
  const float* Wa2 = (const float*)d_in[7];
  const float* ba2 = (const float*)d_in[8];
  float* out = (float*)d_out;

  float* ws = (float*)d_ws;
  float* Ag = ws;                                        // B*N*H floats
  float* Aa = Ag + B_ * N_ * H_;                         // B*N*H floats
  // W arrays padded by 4096 shorts: 1-deep ks-prefetch reads past the end.
  unsigned short* Wghi = (unsigned short*)(Aa + B_ * N_ * H_);  // 65536+4096
  unsigned short* Wglo = Wghi + 65536 + 4096;
  unsigned short* Wahi = Wglo + 65536 + 4096;
  unsigned short* Sfh  = Wahi + 65536 + 4096;            // B*32768
  unsigned short* Sfl  = Sfh + B_ * 32768;

  prep_all<<<dim3(224), dim3(256), 0, stream>>>(
      s, Wg1, bg1, Wa1, ba1, Ag, Aa, Wghi, Wglo, Wahi, Sfh, Sfl);
  score_kernel<<<dim3(B_ * N_), dim3(256), 0, stream>>>(
      s, Ag, Aa, Sfh, Sfl, Wghi, Wglo, Wahi, Wg2, bg2, Wa2, ba2, out);
}

// Round 16
// 243.936 us; speedup vs baseline: 1.0508x; 1.0508x over previous
//
#include <hip/hip_runtime.h>
#include <math.h>

#define B_ 4
#define N_ 256
#define D_ 128
#define H_ 256
#define K_ 8
#define NJP 128   // j per phase (2 phases)

typedef short v8s __attribute__((ext_vector_type(8)));    // 8 bf16 = 4 VGPRs
typedef float v16f __attribute__((ext_vector_type(16)));  // 32x32 MFMA acc

// hi = top-16-bit truncation (x - hi is EXACT); lo = RNE bf16 of remainder.
__device__ inline void split_bf16(float x, unsigned short& hi, unsigned short& lo) {
  unsigned u = __float_as_uint(x);
  unsigned uh = u & 0xFFFF0000u;
  hi = (unsigned short)(uh >> 16);
  float r = x - __uint_as_float(uh);
  unsigned ur = __float_as_uint(r);
  ur += 0x7FFFu + ((ur >> 16) & 1u);
  lo = (unsigned short)(ur >> 16);
}

// ---------------------------------------------------------------------------
// prep_all (R14 version — 1184 blocks; R15's 224-block tiling was slower).
//  blocks 0..1023   : Ag/Aa (i-side first-layer terms, bias folded)
//  blocks 1024..1151: W -> MFMA-B fragment order [ks(16)][tile(8)][lane][8]
//  blocks 1152..1183: sj half of A (i-independent) -> MFMA-A fragment order
// ---------------------------------------------------------------------------
__global__ __launch_bounds__(256) void prep_all(
    const float* __restrict__ s,
    const float* __restrict__ Wg1, const float* __restrict__ bg1,
    const float* __restrict__ Wa1, const float* __restrict__ ba1,
    float* __restrict__ Ag, float* __restrict__ Aa,
    unsigned short* __restrict__ Wghi, unsigned short* __restrict__ Wglo,
    unsigned short* __restrict__ Wahi,
    unsigned short* __restrict__ Sfh, unsigned short* __restrict__ Sfl) {
  __shared__ float sh[D_];
  const int blk = blockIdx.x;
  if (blk < 1024) {
    const int b = blk >> 8, n = blk & 255, h = threadIdx.x;
    if (h < D_) sh[h] = s[(b * N_ + n) * D_ + h];
    __syncthreads();
    float ag = bg1[h], aa = ba1[h];
#pragma unroll 8
    for (int d = 0; d < D_; d++) {
      ag = fmaf(sh[d], Wg1[d * H_ + h], ag);
      aa = fmaf(sh[d], Wa1[d * H_ + h], aa);
    }
    Ag[(b * N_ + n) * H_ + h] = ag;
    Aa[(b * N_ + n) * H_ + h] = aa;
  } else if (blk < 1152) {
    const int id = blk - 1024;          // 0..127
    if (threadIdx.x < 64) {
      const int ks = id >> 3, tile = id & 7, lane = threadIdx.x;
      const int h = tile * 32 + (lane & 31);
      const int kbase = ks * 16 + (lane >> 5) * 8;
      const int idx0 = (id * 64 + lane) * 8;
#pragma unroll
      for (int e = 0; e < 8; e++) {
        const int k = kbase + e;
        const int f = (k < D_) ? (2 * D_ + k) : k;
        unsigned short x, y;
        split_bf16(Wg1[f * H_ + h], x, y);
        Wghi[idx0 + e] = x;
        Wglo[idx0 + e] = y;
        unsigned short xa, ya;
        split_bf16(Wa1[f * H_ + h], xa, ya);
        Wahi[idx0 + e] = xa;
      }
    }
  } else {
    const int id = blk - 1152;          // 0..31
    const int b = id >> 3, jt = id & 7;
    const int lane = threadIdx.x & 63, k0 = threadIdx.x >> 6;
    const int j = jt * 32 + (lane & 31);
#pragma unroll
    for (int ksl = k0; ksl < 8; ksl += 4) {
      const int d = ksl * 16 + (lane >> 5) * 8;
      const float* sp = s + (b * N_ + j) * D_ + d;
      const float4 f0 = *(const float4*)(sp);
      const float4 f1 = *(const float4*)(sp + 4);
      v8s vh, vl;
      unsigned short x, y;
      split_bf16(f0.x, x, y); vh[0] = (short)x; vl[0] = (short)y;
      split_bf16(f0.y, x, y); vh[1] = (short)x; vl[1] = (short)y;
      split_bf16(f0.z, x, y); vh[2] = (short)x; vl[2] = (short)y;
      split_bf16(f0.w, x, y); vh[3] = (short)x; vl[3] = (short)y;
      split_bf16(f1.x, x, y); vh[4] = (short)x; vl[4] = (short)y;
      split_bf16(f1.y, x, y); vh[5] = (short)x; vl[5] = (short)y;
      split_bf16(f1.z, x, y); vh[6] = (short)x; vl[6] = (short)y;
      split_bf16(f1.w, x, y); vh[7] = (short)x; vl[7] = (short)y;
      const int dst = (((b * 8 + jt) * 8 + ksl) * 64 + lane) * 8;
      *(v8s*)(Sfh + dst) = vh;
      *(v8s*)(Sfl + dst) = vl;
    }
  }
}

__device__ inline void arg_better(float v2, int i2, float& v, int& idx) {
  if (v2 > v || (v2 == v && i2 < idx)) { v = v2; idx = i2; }
}

// LDS A-tile (P part, k<128), NJP=128: [jt(4)][ks(8)][half(2)][m32][e(8)]
// jl (0..127), k (0..127); lo half at +16384 shorts.
__device__ inline int a_idx(int jl, int k) {
  return (((jl >> 5) * 8 + (k >> 4)) * 64 + ((k >> 3) & 1) * 32 + (jl & 31)) * 8
         + (k & 7);
}
#define ALO 16384   // shorts offset of lo half

// ---------------------------------------------------------------------------
// score_kernel v16: NJP=128 (2 phases), 4 j-tiles/wave, 2-pass (gate split-3
// then att hi-only; acc 128 AGPR each, shared). Halves the dominant per-ks
// B-frag L2 traffic (same B feeds 2x MFMAs) and halves phase overheads vs
// v14. LDS 64KB P-tile + misc ~70KB -> still 2 blocks/CU.
// ---------------------------------------------------------------------------
__global__ __launch_bounds__(256, 2) void score_kernel(
    const float* __restrict__ s,
    const float* __restrict__ Ag, const float* __restrict__ Aa,
    const unsigned short* __restrict__ Sfh, const unsigned short* __restrict__ Sfl,
    const unsigned short* __restrict__ Wghi, const unsigned short* __restrict__ Wglo,
    const unsigned short* __restrict__ Wahi,
    const float* __restrict__ Wg2, const float* __restrict__ bg2p,
    const float* __restrict__ Wa2, const float* __restrict__ ba2p,
    float* __restrict__ out) {
  const int b = blockIdx.x >> 8;
  const int i = blockIdx.x & 255;
  const int t = threadIdx.x;
  const int wv = t >> 6, lane = t & 63;
  const int m32 = lane & 31, half32 = lane >> 5;

  __shared__ __align__(16) unsigned short a_all[2 * ALO + 64]; // P hi|lo 64KB
  __shared__ float si_sh[D_];
  __shared__ float sc_part[2 * 4 * NJP];   // [net][wv][jl]
  __shared__ float scg_sh[N_];
  __shared__ float attl_sh[N_];
  __shared__ float red_v[4];
  __shared__ int red_i[4];
  __shared__ int sel_list[K_];

  if (t < D_) si_sh[t] = s[(b * N_ + i) * D_ + t];

  float agv[2], w2g[2], aav[2], w2a[2];
#pragma unroll
  for (int ht = 0; ht < 2; ht++) {
    const int hg = wv * 64 + ht * 32 + m32;
    agv[ht] = Ag[(b * N_ + i) * H_ + hg];
    w2g[ht] = Wg2[hg];
    aav[ht] = Aa[(b * N_ + i) * H_ + hg];
    w2a[ht] = Wa2[hg];
  }

  const int boff = ((2 * wv) * 64 + lane) * 8;   // tile pair base; +512 = tile1

#define MF(A_, B_v, C_) C_ = __builtin_amdgcn_mfma_f32_32x32x16_bf16(A_, B_v, C_, 0, 0, 0)

#pragma unroll 1
  for (int ph = 0; ph < 2; ph++) {
    __syncthreads();
    // ---- stage P tile (frag order, k<128): 128 j rows, 64 k per thread ----
    {
      const int jl = t >> 1, kq = t & 1;    // kq: which 64-k half
      const int jg = b * N_ + ph * NJP + jl;
      const float* srow = s + jg * D_ + kq * 64;
      const float* sic = si_sh + kq * 64;
#pragma unroll
      for (int u = 0; u < 8; u++) {   // 8 k per u
        const float4 sv0 = *(const float4*)(srow + u * 8);
        const float4 sv1 = *(const float4*)(srow + u * 8 + 4);
        v8s vh, vl;
        unsigned short x, y;
        split_bf16(sic[u * 8 + 0] * sv0.x, x, y); vh[0] = (short)x; vl[0] = (short)y;
        split_bf16(sic[u * 8 + 1] * sv0.y, x, y); vh[1] = (short)x; vl[1] = (short)y;
        split_bf16(sic[u * 8 + 2] * sv0.z, x, y); vh[2] = (short)x; vl[2] = (short)y;
        split_bf16(sic[u * 8 + 3] * sv0.w, x, y); vh[3] = (short)x; vl[3] = (short)y;
        split_bf16(sic[u * 8 + 4] * sv1.x, x, y); vh[4] = (short)x; vl[4] = (short)y;
        split_bf16(sic[u * 8 + 5] * sv1.y, x, y); vh[5] = (short)x; vl[5] = (short)y;
        split_bf16(sic[u * 8 + 6] * sv1.z, x, y); vh[6] = (short)x; vl[6] = (short)y;
        split_bf16(sic[u * 8 + 7] * sv1.w, x, y); vh[7] = (short)x; vl[7] = (short)y;
        const int idx = a_idx(jl, kq * 64 + u * 8);
        *(v8s*)(a_all + idx) = vh;
        *(v8s*)(a_all + ALO + idx) = vl;
      }
    }
    __syncthreads();

    // sj frag stream bases for this phase (jt stride = 4096 shorts)
    const unsigned short* sf_h = Sfh + ((b * 8 + ph * 4) * 8) * 512 + lane * 8;
    const unsigned short* sf_l = Sfl + ((b * 8 + ph * 4) * 8) * 512 + lane * 8;

    // ================= pass G: gate (split-3), acc 128 AGPR ================
    {
      v16f g[4][2];
#pragma unroll
      for (int jt = 0; jt < 4; jt++)
#pragma unroll
        for (int ht = 0; ht < 2; ht++) g[jt][ht] = (v16f)(0.f);

      const unsigned short* pgh = Wghi + boff;
      const unsigned short* pgl = Wglo + boff;
      v8s bh[2][2], bl[2][2];
      bh[0][0] = *(const v8s*)pgh;  bh[0][1] = *(const v8s*)(pgh + 512);
      bl[0][0] = *(const v8s*)pgl;  bl[0][1] = *(const v8s*)(pgl + 512);
      pgh += 4096;  pgl += 4096;

      const unsigned short* ahp = a_all + lane * 8;
      // ---- loop1: ks 0..7, A from LDS (P part) ----
#pragma unroll 2
      for (int ks = 0; ks < 8; ks++) {
        const int cur = ks & 1, nxt = cur ^ 1;
        bh[nxt][0] = *(const v8s*)pgh;  bh[nxt][1] = *(const v8s*)(pgh + 512);
        bl[nxt][0] = *(const v8s*)pgl;  bl[nxt][1] = *(const v8s*)(pgl + 512);
        pgh += 4096;  pgl += 4096;
        v8s ah0 = *(const v8s*)(ahp);
        v8s ah1 = *(const v8s*)(ahp + 4096);
        v8s ah2 = *(const v8s*)(ahp + 8192);
        v8s ah3 = *(const v8s*)(ahp + 12288);
        v8s al0 = *(const v8s*)(ahp + ALO);
        v8s al1 = *(const v8s*)(ahp + ALO + 4096);
        v8s al2 = *(const v8s*)(ahp + ALO + 8192);
        v8s al3 = *(const v8s*)(ahp + ALO + 12288);
        ahp += 512;
        MF(ah0, bh[cur][0], g[0][0]); MF(ah0, bh[cur][1], g[0][1]);
        MF(ah0, bl[cur][0], g[0][0]); MF(ah0, bl[cur][1], g[0][1]);
        MF(al0, bh[cur][0], g[0][0]); MF(al0, bh[cur][1], g[0][1]);
        MF(ah1, bh[cur][0], g[1][0]); MF(ah1, bh[cur][1], g[1][1]);
        MF(ah1, bl[cur][0], g[1][0]); MF(ah1, bl[cur][1], g[1][1]);
        MF(al1, bh[cur][0], g[1][0]); MF(al1, bh[cur][1], g[1][1]);
        MF(ah2, bh[cur][0], g[2][0]); MF(ah2, bh[cur][1], g[2][1]);
        MF(ah2, bl[cur][0], g[2][0]); MF(ah2, bl[cur][1], g[2][1]);
        MF(al2, bh[cur][0], g[2][0]); MF(al2, bh[cur][1], g[2][1]);
        MF(ah3, bh[cur][0], g[3][0]); MF(ah3, bh[cur][1], g[3][1]);
        MF(ah3, bl[cur][0], g[3][0]); MF(ah3, bl[cur][1], g[3][1]);
        MF(al3, bh[cur][0], g[3][0]); MF(al3, bh[cur][1], g[3][1]);
      }
      // ---- loop2: ks 8..15, A from global sj frag streams ----
      const unsigned short* sh0 = sf_h;
      const unsigned short* sh1 = sf_h + 4096;
      const unsigned short* sh2 = sf_h + 8192;
      const unsigned short* sh3 = sf_h + 12288;
      const unsigned short* sl0 = sf_l;
      const unsigned short* sl1 = sf_l + 4096;
      const unsigned short* sl2 = sf_l + 8192;
      const unsigned short* sl3 = sf_l + 12288;
#pragma unroll 2
      for (int ks = 8; ks < 16; ks++) {
        const int cur = ks & 1, nxt = cur ^ 1;
        bh[nxt][0] = *(const v8s*)pgh;  bh[nxt][1] = *(const v8s*)(pgh + 512);
        bl[nxt][0] = *(const v8s*)pgl;  bl[nxt][1] = *(const v8s*)(pgl + 512);
        pgh += 4096;  pgl += 4096;   // last iter reads pad - harmless
        v8s ah0 = *(const v8s*)sh0;  sh0 += 512;
        v8s ah1 = *(const v8s*)sh1;  sh1 += 512;
        v8s ah2 = *(const v8s*)sh2;  sh2 += 512;
        v8s ah3 = *(const v8s*)sh3;  sh3 += 512;
        v8s al0 = *(const v8s*)sl0;  sl0 += 512;
        v8s al1 = *(const v8s*)sl1;  sl1 += 512;
        v8s al2 = *(const v8s*)sl2;  sl2 += 512;
        v8s al3 = *(const v8s*)sl3;  sl3 += 512;
        MF(ah0, bh[cur][0], g[0][0]); MF(ah0, bh[cur][1], g[0][1]);
        MF(ah0, bl[cur][0], g[0][0]); MF(ah0, bl[cur][1], g[0][1]);
        MF(al0, bh[cur][0], g[0][0]); MF(al0, bh[cur][1], g[0][1]);
        MF(ah1, bh[cur][0], g[1][0]); MF(ah1, bh[cur][1], g[1][1]);
        MF(ah1, bl[cur][0], g[1][0]); MF(ah1, bl[cur][1], g[1][1]);
        MF(al1, bh[cur][0], g[1][0]); MF(al1, bh[cur][1], g[1][1]);
        MF(ah2, bh[cur][0], g[2][0]); MF(ah2, bh[cur][1], g[2][1]);
        MF(ah2, bl[cur][0], g[2][0]); MF(ah2, bl[cur][1], g[2][1]);
        MF(al2, bh[cur][0], g[2][0]); MF(al2, bh[cur][1], g[2][1]);
        MF(ah3, bh[cur][0], g[3][0]); MF(ah3, bh[cur][1], g[3][1]);
        MF(ah3, bl[cur][0], g[3][0]); MF(ah3, bl[cur][1], g[3][1]);
        MF(al3, bh[cur][0], g[3][0]); MF(al3, bh[cur][1], g[3][1]);
      }
      // epilogue G
      float sg[64];
#pragma unroll
      for (int jt = 0; jt < 4; jt++)
#pragma unroll
        for (int r = 0; r < 16; r++) {
          float v = fmaxf(g[jt][0][r] + agv[0], 0.f) * w2g[0]
                  + fmaxf(g[jt][1][r] + agv[1], 0.f) * w2g[1];
#pragma unroll
          for (int off = 1; off <= 16; off <<= 1) v += __shfl_xor(v, off, 64);
          sg[jt * 16 + r] = v;
        }
      if (m32 == 0) {
#pragma unroll
        for (int jt = 0; jt < 4; jt++)
#pragma unroll
          for (int r = 0; r < 16; r++) {
            const int jl = jt * 32 + (r & 3) + 8 * (r >> 2) + 4 * half32;
            sc_part[wv * NJP + jl] = sg[jt * 16 + r];
          }
      }
    }

    // ================= pass A: att (hi-only), acc 128 AGPR =================
    {
      v16f a[4][2];
#pragma unroll
      for (int jt = 0; jt < 4; jt++)
#pragma unroll
        for (int ht = 0; ht < 2; ht++) a[jt][ht] = (v16f)(0.f);

      const unsigned short* pah = Wahi + boff;
      v8s ba[2][2];
      ba[0][0] = *(const v8s*)pah;  ba[0][1] = *(const v8s*)(pah + 512);
      pah += 4096;

      const unsigned short* ahp = a_all + lane * 8;
#pragma unroll 2
      for (int ks = 0; ks < 8; ks++) {
        const int cur = ks & 1, nxt = cur ^ 1;
        ba[nxt][0] = *(const v8s*)pah;  ba[nxt][1] = *(const v8s*)(pah + 512);
        pah += 4096;
        v8s ah0 = *(const v8s*)(ahp);
        v8s ah1 = *(const v8s*)(ahp + 4096);
        v8s ah2 = *(const v8s*)(ahp + 8192);
        v8s ah3 = *(const v8s*)(ahp + 12288);
        ahp += 512;
        MF(ah0, ba[cur][0], a[0][0]); MF(ah0, ba[cur][1], a[0][1]);
        MF(ah1, ba[cur][0], a[1][0]); MF(ah1, ba[cur][1], a[1][1]);
        MF(ah2, ba[cur][0], a[2][0]); MF(ah2, ba[cur][1], a[2][1]);
        MF(ah3, ba[cur][0], a[3][0]); MF(ah3, ba[cur][1], a[3][1]);
      }
      const unsigned short* sh0 = sf_h;
      const unsigned short* sh1 = sf_h + 4096;
      const unsigned short* sh2 = sf_h + 8192;
      const unsigned short* sh3 = sf_h + 12288;
#pragma unroll 2
      for (int ks = 8; ks < 16; ks++) {
        const int cur = ks & 1, nxt = cur ^ 1;
        ba[nxt][0] = *(const v8s*)pah;  ba[nxt][1] = *(const v8s*)(pah + 512);
        pah += 4096;   // last iter reads pad
        v8s ah0 = *(const v8s*)sh0;  sh0 += 512;
        v8s ah1 = *(const v8s*)sh1;  sh1 += 512;
        v8s ah2 = *(const v8s*)sh2;  sh2 += 512;
        v8s ah3 = *(const v8s*)sh3;  sh3 += 512;
        MF(ah0, ba[cur][0], a[0][0]); MF(ah0, ba[cur][1], a[0][1]);
        MF(ah1, ba[cur][0], a[1][0]); MF(ah1, ba[cur][1], a[1][1]);
        MF(ah2, ba[cur][0], a[2][0]); MF(ah2, ba[cur][1], a[2][1]);
        MF(ah3, ba[cur][0], a[3][0]); MF(ah3, ba[cur][1], a[3][1]);
      }
      // epilogue A
      float sa[64];
#pragma unroll
      for (int jt = 0; jt < 4; jt++)
#pragma unroll
        for (int r = 0; r < 16; r++) {
          float v = fmaxf(a[jt][0][r] + aav[0], 0.f) * w2a[0]
                  + fmaxf(a[jt][1][r] + aav[1], 0.f) * w2a[1];
#pragma unroll
          for (int off = 1; off <= 16; off <<= 1) v += __shfl_xor(v, off, 64);
          sa[jt * 16 + r] = v;
        }
      if (m32 == 0) {
#pragma unroll
        for (int jt = 0; jt < 4; jt++)
#pragma unroll
          for (int r = 0; r < 16; r++) {
            const int jl = jt * 32 + (r & 3) + 8 * (r >> 2) + 4 * half32;
            sc_part[4 * NJP + wv * NJP + jl] = sa[jt * 16 + r];
          }
      }
    }
    __syncthreads();
    if (t < NJP) {
      scg_sh[ph * NJP + t] = sc_part[t] + sc_part[NJP + t] + sc_part[2 * NJP + t]
                           + sc_part[3 * NJP + t] + bg2p[0];
    } else {
      const int jl = t - NJP;
      attl_sh[ph * NJP + jl] = sc_part[4 * NJP + jl] + sc_part[5 * NJP + jl]
                             + sc_part[6 * NJP + jl] + sc_part[7 * NJP + jl] + ba2p[0];
    }
  }
  __syncthreads();

  // ---- top-8 over j: value desc, index asc ----
  for (int k = 0; k < K_; k++) {
    float v = scg_sh[t];
    int idx = t;
#pragma unroll
    for (int off = 32; off > 0; off >>= 1) {
      const float vo = __shfl_down(v, off, 64);
      const int io = __shfl_down(idx, off, 64);
      arg_better(vo, io, v, idx);
    }
    if ((t & 63) == 0) { red_v[t >> 6] = v; red_i[t >> 6] = idx; }
    __syncthreads();
    if (t == 0) {
      float bv = red_v[0];
      int bi = red_i[0];
      for (int w = 1; w < 4; w++) arg_better(red_v[w], red_i[w], bv, bi);
      sel_list[k] = bi;
      scg_sh[bi] = -INFINITY;
    }
    __syncthreads();
  }

  bool selj = false;
#pragma unroll
  for (int k = 0; k < K_; k++) selj = selj || (sel_list[k] == t);

  if (t == 0) {
    float m = -INFINITY;
    for (int k = 0; k < K_; k++) m = fmaxf(m, attl_sh[sel_list[k]]);
    float ssum = 0.f;
    for (int k = 0; k < K_; k++) ssum += expf(attl_sh[sel_list[k]] - m);
    red_v[0] = m;
    red_v[1] = ssum;
  }
  __syncthreads();
  const float att = selj ? expf(attl_sh[t] - red_v[0]) / red_v[1] : 0.f;

  float* __restrict__ ctx_out = out;
  float* __restrict__ gate_out = out + B_ * N_ * D_;
  float* __restrict__ att_out = out + B_ * N_ * D_ + B_ * N_ * N_;

  const int row = (b * N_ + i) * N_;
  gate_out[row + t] = selj ? 1.f : 0.f;
  att_out[row + t] = att;

  __syncthreads();
  attl_sh[t] = att;
  __syncthreads();

  if (t < D_) {
    float acc2 = 0.f;
#pragma unroll
    for (int k = 0; k < K_; k++) {
      const int jj = sel_list[k];
      acc2 = fmaf(attl_sh[jj], s[(b * N_ + jj) * D_ + t], acc2);
    }
    ctx_out[(b * N_ + i) * D_ + t] = acc2;
  }
#undef MF
}

extern "C" void kernel_launch(void* const* d_in, const int* in_sizes, int n_in,
                              void* d_out, int out_size, void* d_ws, size_t ws_size,
                              hipStream_t stream) {
  const float* s   = (const float*)d_in[0];
  const float* Wg1 = (const float*)d_in[1];
  const float* bg1 = (const float*)d_in[2];
  const float* Wg2 = (const float*)d_in[3];
  const float* bg2 = (const float*)d_in[4];
  const float* Wa1 = (const float*)d_in[5];
  const float* ba1 = (const float*)d_in[6];
  const float* Wa2 = (const float*)d_in[7];
  const float* ba2 = (const float*)d_in[8];
  float* out = (float*)d_out;

  float* ws = (float*)d_ws;
  float* Ag = ws;                                        // B*N*H floats
  float* Aa = Ag + B_ * N_ * H_;                         // B*N*H floats
  // W arrays padded by 4096 shorts: 1-deep ks-prefetch reads past the end.
  unsigned short* Wghi = (unsigned short*)(Aa + B_ * N_ * H_);  // 65536+4096
  unsigned short* Wglo = Wghi + 65536 + 4096;
  unsigned short* Wahi = Wglo + 65536 + 4096;
  unsigned short* Sfh  = Wahi + 65536 + 4096;            // B*32768
  unsigned short* Sfl  = Sfh + B_ * 32768;

  prep_all<<<dim3(1184), dim3(256), 0, stream>>>(
      s, Wg1, bg1, Wa1, ba1, Ag, Aa, Wghi, Wglo, Wahi, Sfh, Sfl);
  score_kernel<<<dim3(B_ * N_), dim3(256), 0, stream>>>(
      s, Ag, Aa, Sfh, Sfl, Wghi, Wglo, Wahi, Wg2, bg2, Wa2, ba2, out);
}